// Round 10
// baseline (229.362 us; speedup 1.0000x reference)
//
#include <hip/hip_runtime.h>
#include <math.h>

#define B_ 16
#define N_ 576
#define C_ 768
#define NH 12
#define D_ 64
#define STR 68    // attention LDS row stride (ushorts)
#define QKV 2304  // fused QKV output row width

typedef unsigned short u16;
typedef unsigned int u32;
typedef __bf16 bf16x8 __attribute__((ext_vector_type(8)));
typedef float f32x4 __attribute__((ext_vector_type(4)));

// native RNE f32->bf16 (compiler emits v_cvt_pk_bf16_f32 for pairs)
__device__ __forceinline__ u16 f2bf(float f) {
    return __builtin_bit_cast(u16, (__bf16)f);
}

// 8B-granular LDS frag read (STR=68 rows are only 8B-aligned)
__device__ __forceinline__ bf16x8 ldsF8u(const u16* p) {
    union { uint2 u[2]; bf16x8 v; } t;
    t.u[0] = *(const uint2*)p;
    t.u[1] = *(const uint2*)(p + 4);
    return t.v;
}
// 16B-aligned LDS frag read
__device__ __forceinline__ bf16x8 ldsF8a(const u16* p) {
    union { uint4 u; bf16x8 v; } t;
    t.u = *(const uint4*)p;
    return t.v;
}

// async global->LDS, 16B/lane; LDS dest = wave-uniform base + lane*16
__device__ __forceinline__ void gload16(const u16* g, u16* l) {
    __builtin_amdgcn_global_load_lds(
        (const __attribute__((address_space(1))) void*)g,
        (__attribute__((address_space(3))) void*)l,
        16, 0, 0);
}

// ---------------------------------------------------------------------------
// Fused prep, block-efficient layout (5760 blocks):
//   [0,1728):    conv_x, 4 x float4 per thread
//   [1728,4032): transpose_w 32x32 tiles (4 matrices)
//   [4032,5760): pos_softmax, wave-per-row in registers (9 vals/lane)
// ---------------------------------------------------------------------------
__global__ __launch_bounds__(256)
void prep_kernel(const float* __restrict__ x,
                 const float* __restrict__ Wq,
                 const float* __restrict__ Wk,
                 const float* __restrict__ Wv,
                 const float* __restrict__ Wproj,
                 const float* __restrict__ pos_w,
                 const float* __restrict__ pos_b,
                 const int* __restrict__ Wp,
                 u16* __restrict__ xb,
                 u16* __restrict__ wt,
                 u16* __restrict__ wtp,
                 u16* __restrict__ posb)
{
    __shared__ float sh[32 * 33];          // transpose tile only
    const int id = blockIdx.x;
    const int tid = threadIdx.x;

    if (id < 1728) {
        // ---- x fp32 -> bf16, 4 x float4 per thread ----
#pragma unroll
        for (int p = 0; p < 4; ++p) {
            int i = id * 1024 + p * 256 + tid;
            float4 v = ((const float4*)x)[i];
            u16 o[4] = {f2bf(v.x), f2bf(v.y), f2bf(v.z), f2bf(v.w)};
            *(uint2*)&xb[(size_t)i * 4] = *(const uint2*)o;
        }
    } else if (id < 4032) {
        // ---- W [768][768] fp32 -> W^T bf16, 32x32 tile ----
        int sub = id - 1728;
        int w = sub / 576;
        int s2 = sub - w * 576;
        const float* src = (w == 0) ? Wq : (w == 1) ? Wk : (w == 2) ? Wv : Wproj;
        u16* dst = (w < 3) ? (wt + (size_t)w * C_ * C_) : wtp;
        float (*t)[33] = (float(*)[33])sh;
        const int bx = (s2 % 24) * 32, by = (s2 / 24) * 32;
        const int tx = tid & 31, ty = tid >> 5;
#pragma unroll
        for (int i = 0; i < 32; i += 8)
            t[ty + i][tx] = src[(size_t)(by + ty + i) * C_ + bx + tx];
        __syncthreads();
#pragma unroll
        for (int i = 0; i < 32; i += 8)
            dst[(size_t)(bx + ty + i) * C_ + by + tx] = f2bf(t[tx][ty + i]);
    } else {
        // ---- positional softmax, wave-per-row ----
        int sub = id - 4032;                 // 0..1727
        const int hh = sub / 144;
        const int n = (sub % 144) * 4 + (tid >> 6);
        const int lane = tid & 63;
        const int Ww = Wp[0];                // 24
        const float w0 = pos_w[0 * NH + hh];
        const float w1 = pos_w[1 * NH + hh];
        const float w2 = pos_w[2 * NH + hh];
        const float bb = pos_b[hh];
        const int nx = n % Ww, ny = n / Ww;

        int mx = lane % Ww, my = lane / Ww;
        const int stepx = 64 - 2 * Ww;       // 16 for Ww=24
        float e[9];
        float lmax = -1e30f;
#pragma unroll
        for (int k = 0; k < 9; ++k) {
            float dx = (float)(mx - nx);
            float dy = (float)(my - ny);
            float sc = fmaf(dx, w0, fmaf(dy, w1, fmaf(dx * dx + dy * dy, w2, bb)));
            e[k] = sc;
            lmax = fmaxf(lmax, sc);
            mx += stepx; my += 2;
            if (mx >= Ww) { mx -= Ww; my += 1; }
        }
#pragma unroll
        for (int off = 32; off; off >>= 1)
            lmax = fmaxf(lmax, __shfl_xor(lmax, off, 64));
        float lsum = 0.f;
#pragma unroll
        for (int k = 0; k < 9; ++k) {
            float ex = __expf(e[k] - lmax);
            e[k] = ex;
            lsum += ex;
        }
#pragma unroll
        for (int off = 32; off; off >>= 1)
            lsum += __shfl_xor(lsum, off, 64);
        const float inv = 1.0f / lsum;

        u16* op = posb + ((size_t)hh * N_ + n) * N_;
#pragma unroll
        for (int k = 0; k < 9; ++k)
            op[k * 64 + lane] = f2bf(e[k] * inv);
    }
}

// ---------------------------------------------------------------------------
// V section of qkvb [m][2304] -> vtb [B,NH,D,N]  (64x64 LDS transpose)
// ---------------------------------------------------------------------------
__global__ __launch_bounds__(256)
void transpose_v_kernel(const u16* __restrict__ qkvb, u16* __restrict__ vtb)
{
    __shared__ u16 t[64 * 72];
    const int n0 = blockIdx.x * 64;
    const int bh = blockIdx.y;
    const int b = bh / NH, h = bh % NH;
    const int tid = threadIdx.x;
    const u16* src = qkvb + ((size_t)b * N_ + n0) * QKV + 2 * C_ + h * D_;
#pragma unroll
    for (int p = 0; p < 2; ++p) {
        int idx = p * 256 + tid;
        int r = idx >> 3, c = (idx & 7) << 3;
        *(uint4*)&t[r * 72 + c] = *(const uint4*)(src + (size_t)r * QKV + c);
    }
    __syncthreads();
    u16* dst = vtb + (size_t)bh * D_ * N_ + n0;
#pragma unroll
    for (int p = 0; p < 2; ++p) {
        int idx = p * 256 + tid;
        int dd = idx >> 3, n8 = (idx & 7) << 3;
        u16 o[8];
#pragma unroll
        for (int j = 0; j < 8; ++j) o[j] = t[(n8 + j) * 72 + dd];
        *(uint4*)(dst + (size_t)dd * N_ + n8) = *(const uint4*)o;
    }
}

// ---------------------------------------------------------------------------
// bf16 MFMA GEMM: 128x128 tile, BK=64, 4 waves, 4x4 16x16x32 per wave.
// XOR-swizzled LDS staging (source-side pre-swizzle, linear LDS dest).
// XCD-chunked block swizzle (nwg % 8 == 0 at both call sites).
// mode 0: out fp32 [M][768] + bias (projection)
// mode 1: outb bf16 [M][2304], Q section (tn<768) scaled by 0.125
// ---------------------------------------------------------------------------
__global__ __launch_bounds__(256)
void mfma_gemm(const u16* __restrict__ A,
               const u16* __restrict__ BT,
               const float* __restrict__ bias,
               float* __restrict__ out,
               u16* __restrict__ outb,
               int ldo, int mode)
{
    const int K = C_;
    __shared__ __align__(16) u16 As[128 * 64];
    __shared__ __align__(16) u16 Bs[128 * 64];
    const int tid = threadIdx.x;
    const int wave = tid >> 6, lane = tid & 63;
    const int quad = lane >> 4, l16 = lane & 15;
    const int wy = wave >> 1, wx = wave & 1;

    // XCD swizzle: nwg % 8 == 0 at both call sites (1296, 432)
    const int gx = gridDim.x;
    const int nwg = gx * gridDim.y;
    int o = blockIdx.y * gx + blockIdx.x;
    o = (o & 7) * (nwg >> 3) + (o >> 3);
    const int tm = (o / gx) * 128, tn = (o % gx) * 128;

    const int lr = lane >> 3;            // row within 8-row staging group
    const int sc = ((lane & 7) ^ lr) * 8; // swizzled source col (elems)

    f32x4 acc[4][4];
#pragma unroll
    for (int i = 0; i < 4; ++i)
#pragma unroll
        for (int j = 0; j < 4; ++j)
            acc[i][j] = (f32x4){0.f, 0.f, 0.f, 0.f};

    for (int k0 = 0; k0 < K; k0 += 64) {
        __syncthreads();
#pragma unroll
        for (int t = 0; t < 4; ++t) {
            const int rg = wave * 32 + t * 8;
            gload16(A  + (size_t)(tm + rg + lr) * K + k0 + sc, &As[rg * 64]);
            gload16(BT + (size_t)(tn + rg + lr) * K + k0 + sc, &Bs[rg * 64]);
        }
        __syncthreads();

#pragma unroll
        for (int kh = 0; kh < 2; ++kh) {
            bf16x8 aA[4], bB[4];
#pragma unroll
            for (int i = 0; i < 4; ++i) {
                const int s = (kh * 4 + quad) ^ (l16 & 7);
                aA[i] = ldsF8a(&As[(wy * 64 + i * 16 + l16) * 64 + s * 8]);
            }
#pragma unroll
            for (int j = 0; j < 4; ++j) {
                const int s = (kh * 4 + quad) ^ (l16 & 7);
                bB[j] = ldsF8a(&Bs[(wx * 64 + j * 16 + l16) * 64 + s * 8]);
            }
#pragma unroll
            for (int i = 0; i < 4; ++i)
#pragma unroll
                for (int j = 0; j < 4; ++j)
                    acc[i][j] = __builtin_amdgcn_mfma_f32_16x16x32_bf16(aA[i], bB[j], acc[i][j], 0, 0, 0);
        }
    }

    if (mode == 0) {
#pragma unroll
        for (int i = 0; i < 4; ++i) {
#pragma unroll
            for (int r = 0; r < 4; ++r) {
                const int m = tm + wy * 64 + i * 16 + quad * 4 + r;
#pragma unroll
                for (int j = 0; j < 4; ++j) {
                    const int c = tn + wx * 64 + j * 16 + l16;
                    out[(size_t)m * ldo + c] = acc[i][j][r] + bias[c];
                }
            }
        }
    } else {
        const float scale = (tn < C_) ? 0.125f : 1.0f;
#pragma unroll
        for (int i = 0; i < 4; ++i) {
#pragma unroll
            for (int r = 0; r < 4; ++r) {
                const int m = tm + wy * 64 + i * 16 + quad * 4 + r;
#pragma unroll
                for (int j = 0; j < 4; ++j) {
                    const int c = tn + wx * 64 + j * 16 + l16;
                    outb[(size_t)m * ldo + c] = f2bf(acc[i][j][r] * scale);
                }
            }
        }
    }
}

// ---------------------------------------------------------------------------
// Flash-style MFMA attention with SWAPPED QK^T + in-register P transpose.
// zs = mfma(K_frag, Q_frag) gives S^T: lane (quad,l16) holds
// S[q = wave*16 + l16][m = nt*16 + quad*4 + r] -- the lane's 16 values all
// belong to its OWN q-row, so the PV A-fragment P[q=l16][m=ks*32+quad*8+e]
// is built in-register: exp -> bf16-pair pack (cvt_pk) -> 16 shfl + selects
// across the 4 lanes sharing l16.  This removes the P LDS tile (16 scalar
// ds_write_u16 + lgkmcnt(0) drain + 4 ds_read_b64 per iter) and shrinks
// LDS 34.8->25.5 KB (blocks/CU cap 4->6).
// Index algebra: m = ks*32+quad_d*8+e  =>  nt = 2ks+(quad_d>>1),
// src quad = 2*(quad_d&1) + (e>>2), r = e&3.
// XCD-chunked dispatch swizzle (1728 % 8 == 0) as before.
// ---------------------------------------------------------------------------
__global__ __launch_bounds__(256)
void attn_kernel(const u16* __restrict__ qkvb,
                 const u16* __restrict__ vt,
                 const u16* __restrict__ pos,
                 const float* __restrict__ gating,
                 u16* __restrict__ ao)
{
    const int gx = gridDim.x;                   // 9
    const int nwg = gx * gridDim.y;             // 1728
    int o = blockIdx.y * gx + blockIdx.x;
    o = (o & 7) * (nwg >> 3) + (o >> 3);        // XCD-chunked, bijective
    const int qt = o % gx;
    const int yb = o / gx;                      // h*16 + b  (h-major)
    const int h = yb >> 4, b = yb & 15;
    const int tid = threadIdx.x;
    const int wave = tid >> 6, lane = tid & 63;
    const int quad = lane >> 4, l16 = lane & 15;

    __shared__ u16 smem[3 * 64 * STR];
    u16* Kt = smem;                  // K tile [m'][d]; Q tile during prologue
    u16* Vs = smem + 64 * STR;       // V^T tile [dd][m']
    u16* Pp = smem + 2 * 64 * STR;   // pos tile [qr][m']

    const u16* qptr  = qkvb + ((size_t)b * N_ + qt * 64) * QKV + h * D_;
    const u16* kbase = qkvb + (size_t)b * N_ * QKV + C_ + h * D_;
    const u16* vbase = vt + (size_t)(b * NH + h) * D_ * N_;   // vtb layout key
    const u16* pbase = pos + ((size_t)h * N_ + qt * 64) * N_;

    const int sr = tid >> 3;            // 0..31 (two passes cover 64 rows)
    const int scol = (tid & 7) << 3;    // 0..56

    // stage Q into Kt (prologue only; overwritten by first writeT)
#pragma unroll
    for (int p = 0; p < 2; ++p) {
        int r = p * 32 + sr;
        uint4 d = *(const uint4*)(qptr + (size_t)r * QKV + scol);
        *(uint2*)&Kt[r * STR + scol]     = make_uint2(d.x, d.y);
        *(uint2*)&Kt[r * STR + scol + 4] = make_uint2(d.z, d.w);
    }
    __syncthreads();

    const int arow = wave * 16 + l16;
    bf16x8 aq0 = ldsF8u(&Kt[arow * STR + quad * 8]);
    bf16x8 aq1 = ldsF8u(&Kt[arow * STR + 32 + quad * 8]);

    uint4 rk[2], rv[2], rp[2];
    auto loadT = [&](int m0) {
#pragma unroll
        for (int p = 0; p < 2; ++p) {
            int r = p * 32 + sr;
            rk[p] = *(const uint4*)(kbase + (size_t)(m0 + r) * QKV + scol);
            rv[p] = *(const uint4*)(vbase + (size_t)r * N_ + m0 + scol);
            rp[p] = *(const uint4*)(pbase + (size_t)r * N_ + m0 + scol);
        }
    };
    auto writeT = [&]() {
#pragma unroll
        for (int p = 0; p < 2; ++p) {
            int r = p * 32 + sr;
            *(uint2*)&Kt[r * STR + scol]     = make_uint2(rk[p].x, rk[p].y);
            *(uint2*)&Kt[r * STR + scol + 4] = make_uint2(rk[p].z, rk[p].w);
            *(uint2*)&Vs[r * STR + scol]     = make_uint2(rv[p].x, rv[p].y);
            *(uint2*)&Vs[r * STR + scol + 4] = make_uint2(rv[p].z, rv[p].w);
            *(uint2*)&Pp[r * STR + scol]     = make_uint2(rp[p].x, rp[p].y);
            *(uint2*)&Pp[r * STR + scol + 4] = make_uint2(rp[p].z, rp[p].w);
        }
    };

    loadT(0);

    f32x4 oc[4], op[4];
#pragma unroll
    for (int nt = 0; nt < 4; ++nt) {
        oc[nt] = (f32x4){0.f, 0.f, 0.f, 0.f};
        op[nt] = (f32x4){0.f, 0.f, 0.f, 0.f};
    }
    float lrun = 0.f;                    // row q = arow partial sum

    const int srcA = ((quad & 1) << 5) + l16;   // lane 2*(quad&1)*16 + l16
    const int srcB = srcA + 16;
    const int hi = quad >> 1;

    for (int mt = 0; mt < 9; ++mt) {
        // prev compute's LDS reads done (and, at mt=0, Q frag reads done)
        __syncthreads();
        writeT();
        __syncthreads();
        if (mt < 8) loadT((mt + 1) * 64);   // async; consumed next iter

        // S^T = K @ Q^T (swapped operands): lane holds row q=arow,
        // m = nt*16 + quad*4 + r
        f32x4 s[4];
#pragma unroll
        for (int nt = 0; nt < 4; ++nt) {
            bf16x8 b0 = ldsF8u(&Kt[(nt * 16 + l16) * STR + quad * 8]);
            bf16x8 b1 = ldsF8u(&Kt[(nt * 16 + l16) * STR + 32 + quad * 8]);
            f32x4 z = (f32x4){0.f, 0.f, 0.f, 0.f};
            z = __builtin_amdgcn_mfma_f32_16x16x32_bf16(b0, aq0, z, 0, 0, 0);
            z = __builtin_amdgcn_mfma_f32_16x16x32_bf16(b1, aq1, z, 0, 0, 0);
            s[nt] = z;
        }

        // P = exp(S^T), packed to bf16 pairs; lane-local row sum
        u32 pk[4][2];
#pragma unroll
        for (int nt = 0; nt < 4; ++nt) {
            float e0 = __expf(s[nt][0]);
            float e1 = __expf(s[nt][1]);
            float e2 = __expf(s[nt][2]);
            float e3 = __expf(s[nt][3]);
            lrun += (e0 + e1) + (e2 + e3);
            pk[nt][0] = (u32)f2bf(e0) | ((u32)f2bf(e1) << 16);
            pk[nt][1] = (u32)f2bf(e2) | ((u32)f2bf(e3) << 16);
        }

        // build PV A-frags in-register via cross-quad shfl
        bf16x8 app[2];
#pragma unroll
        for (int ks = 0; ks < 2; ++ks) {
            u32 xa = (u32)__shfl((int)pk[2 * ks][0],     srcA, 64);
            u32 xb = (u32)__shfl((int)pk[2 * ks + 1][0], srcA, 64);
            u32 ya = (u32)__shfl((int)pk[2 * ks][1],     srcA, 64);
            u32 yb = (u32)__shfl((int)pk[2 * ks + 1][1], srcA, 64);
            u32 za = (u32)__shfl((int)pk[2 * ks][0],     srcB, 64);
            u32 zb = (u32)__shfl((int)pk[2 * ks + 1][0], srcB, 64);
            u32 wa = (u32)__shfl((int)pk[2 * ks][1],     srcB, 64);
            u32 wb = (u32)__shfl((int)pk[2 * ks + 1][1], srcB, 64);
            union { uint4 u; bf16x8 v; } t;
            t.u.x = hi ? xb : xa;
            t.u.y = hi ? yb : ya;
            t.u.z = hi ? zb : za;
            t.u.w = hi ? wb : wa;
            app[ks] = t.v;
        }

        // O_c += P @ V ; O_p += pos @ V
#pragma unroll
        for (int ks = 0; ks < 2; ++ks) {
            bf16x8 apos = ldsF8u(&Pp[arow * STR + ks * 32 + quad * 8]);
#pragma unroll
            for (int nt = 0; nt < 4; ++nt) {
                bf16x8 bv = ldsF8u(&Vs[(nt * 16 + l16) * STR + ks * 32 + quad * 8]);
                oc[nt] = __builtin_amdgcn_mfma_f32_16x16x32_bf16(app[ks], bv, oc[nt], 0, 0, 0);
                op[nt] = __builtin_amdgcn_mfma_f32_16x16x32_bf16(apos,    bv, op[nt], 0, 0, 0);
            }
        }
    }

    // full denominator for row q = arow (reduce the 4 quads sharing l16)
    lrun += __shfl_xor(lrun, 16, 64);
    lrun += __shfl_xor(lrun, 32, 64);

    const float g = 1.f / (1.f + __expf(-gating[h]));
#pragma unroll
    for (int r = 0; r < 4; ++r) {
        // row quad*4+r's denominator lives in lane l16 == quad*4+r
        const float lp = __shfl(lrun, quad * 4 + r, 64);
        const float sc = (1.f - g) / lp;
        const int row = qt * 64 + wave * 16 + quad * 4 + r;
#pragma unroll
        for (int nt = 0; nt < 4; ++nt) {
            ao[((size_t)b * N_ + row) * C_ + h * D_ + nt * 16 + l16] =
                f2bf(oc[nt][r] * sc + g * op[nt][r]);
        }
    }
}

// ---------------------------------------------------------------------------
extern "C" void kernel_launch(void* const* d_in, const int* in_sizes, int n_in,
                              void* d_out, int out_size, void* d_ws, size_t ws_size,
                              hipStream_t stream)
{
    const float* x      = (const float*)d_in[0];
    const float* Wq     = (const float*)d_in[1];
    const float* Wk     = (const float*)d_in[2];
    const float* Wv     = (const float*)d_in[3];
    const float* Wproj  = (const float*)d_in[4];
    const float* bproj  = (const float*)d_in[5];
    const float* pos_w  = (const float*)d_in[6];
    const float* pos_b  = (const float*)d_in[7];
    const float* gating = (const float*)d_in[8];
    const int*   Wp     = (const int*)d_in[10];
    float* out = (float*)d_out;

    const size_t xe = (size_t)B_ * N_ * C_;        // 7,077,888
    const size_t we = (size_t)C_ * C_;             // 589,824
    const size_t qe = (size_t)B_ * N_ * QKV;       // 21,233,664
    const size_t pe = (size_t)NH * N_ * N_;        // 3,981,312
    u16* xb   = (u16*)d_ws;
    u16* wt   = xb + xe;            // packed [2304][768]: WqT | WkT | WvT
    u16* wtp  = wt + 3 * we;        // WprojT
    u16* qkvb = wtp + we;           // [M][2304] bf16: Q | K | V
    u16* vtb  = qkvb + qe;          // [B,NH,D,N]
    u16* posb = vtb + xe;
    u16* aob  = posb + pe;
    size_t need = (size_t)(3 * xe + 4 * we + qe + pe) * sizeof(u16);  // ~97.6 MB
    if (ws_size < need) return;

    // fused prep: conv_x | 4x transpose_w | pos_softmax  (1 launch, 5760 blocks)
    prep_kernel<<<dim3(5760), 256, 0, stream>>>(x, Wq, Wk, Wv, Wproj,
                                                pos_w, pos_b, Wp,
                                                xb, wt, wtp, posb);
    // fused QKV: bf16 [9216][2304]
    mfma_gemm<<<dim3(18, 72), 256, 0, stream>>>(xb, wt, nullptr, nullptr,
                                                qkvb, QKV, 1);
    transpose_v_kernel<<<dim3(9, B_ * NH), 256, 0, stream>>>(qkvb, vtb);
    attn_kernel<<<dim3(9, NH * B_), 256, 0, stream>>>(qkvb, vtb, posb, gating, aob);
    // projection: fp32 out + bias
    mfma_gemm<<<dim3(6, 72), 256, 0, stream>>>(aob, wtp, bproj, out,
                                               nullptr, C_, 0);
}

// Round 11
// 224.073 us; speedup vs baseline: 1.0236x; 1.0236x over previous
//
#include <hip/hip_runtime.h>
#include <math.h>

#define B_ 16
#define N_ 576
#define C_ 768
#define NH 12
#define D_ 64
#define STR 68    // attention LDS row stride (ushorts)
#define QKV 2304  // fused QKV output row width

typedef unsigned short u16;
typedef __bf16 bf16x8 __attribute__((ext_vector_type(8)));
typedef float f32x4 __attribute__((ext_vector_type(4)));

// native RNE f32->bf16 (compiler emits v_cvt_pk_bf16_f32 for pairs)
__device__ __forceinline__ u16 f2bf(float f) {
    return __builtin_bit_cast(u16, (__bf16)f);
}

// 8B-granular LDS frag read (STR=68 rows are only 8B-aligned)
__device__ __forceinline__ bf16x8 ldsF8u(const u16* p) {
    union { uint2 u[2]; bf16x8 v; } t;
    t.u[0] = *(const uint2*)p;
    t.u[1] = *(const uint2*)(p + 4);
    return t.v;
}
// 16B-aligned LDS frag read
__device__ __forceinline__ bf16x8 ldsF8a(const u16* p) {
    union { uint4 u; bf16x8 v; } t;
    t.u = *(const uint4*)p;
    return t.v;
}

// async global->LDS, 16B/lane; LDS dest = wave-uniform base + lane*16
__device__ __forceinline__ void gload16(const u16* g, u16* l) {
    __builtin_amdgcn_global_load_lds(
        (const __attribute__((address_space(1))) void*)g,
        (__attribute__((address_space(3))) void*)l,
        16, 0, 0);
}

// ---------------------------------------------------------------------------
// Fused prep, block-efficient layout (5760 blocks):
//   [0,1728):    conv_x, 4 x float4 per thread
//   [1728,4032): transpose_w 32x32 tiles (4 matrices)
//   [4032,5760): pos_softmax, wave-per-row in registers (9 vals/lane)
// ---------------------------------------------------------------------------
__global__ __launch_bounds__(256)
void prep_kernel(const float* __restrict__ x,
                 const float* __restrict__ Wq,
                 const float* __restrict__ Wk,
                 const float* __restrict__ Wv,
                 const float* __restrict__ Wproj,
                 const float* __restrict__ pos_w,
                 const float* __restrict__ pos_b,
                 const int* __restrict__ Wp,
                 u16* __restrict__ xb,
                 u16* __restrict__ wt,
                 u16* __restrict__ wtp,
                 u16* __restrict__ posb)
{
    __shared__ float sh[32 * 33];          // transpose tile only
    const int id = blockIdx.x;
    const int tid = threadIdx.x;

    if (id < 1728) {
        // ---- x fp32 -> bf16, 4 x float4 per thread ----
#pragma unroll
        for (int p = 0; p < 4; ++p) {
            int i = id * 1024 + p * 256 + tid;
            float4 v = ((const float4*)x)[i];
            u16 o[4] = {f2bf(v.x), f2bf(v.y), f2bf(v.z), f2bf(v.w)};
            *(uint2*)&xb[(size_t)i * 4] = *(const uint2*)o;
        }
    } else if (id < 4032) {
        // ---- W [768][768] fp32 -> W^T bf16, 32x32 tile ----
        int sub = id - 1728;
        int w = sub / 576;
        int s2 = sub - w * 576;
        const float* src = (w == 0) ? Wq : (w == 1) ? Wk : (w == 2) ? Wv : Wproj;
        u16* dst = (w < 3) ? (wt + (size_t)w * C_ * C_) : wtp;
        float (*t)[33] = (float(*)[33])sh;
        const int bx = (s2 % 24) * 32, by = (s2 / 24) * 32;
        const int tx = tid & 31, ty = tid >> 5;
#pragma unroll
        for (int i = 0; i < 32; i += 8)
            t[ty + i][tx] = src[(size_t)(by + ty + i) * C_ + bx + tx];
        __syncthreads();
#pragma unroll
        for (int i = 0; i < 32; i += 8)
            dst[(size_t)(bx + ty + i) * C_ + by + tx] = f2bf(t[tx][ty + i]);
    } else {
        // ---- positional softmax, wave-per-row ----
        int sub = id - 4032;                 // 0..1727
        const int hh = sub / 144;
        const int n = (sub % 144) * 4 + (tid >> 6);
        const int lane = tid & 63;
        const int Ww = Wp[0];                // 24
        const float w0 = pos_w[0 * NH + hh];
        const float w1 = pos_w[1 * NH + hh];
        const float w2 = pos_w[2 * NH + hh];
        const float bb = pos_b[hh];
        const int nx = n % Ww, ny = n / Ww;

        int mx = lane % Ww, my = lane / Ww;
        const int stepx = 64 - 2 * Ww;       // 16 for Ww=24
        float e[9];
        float lmax = -1e30f;
#pragma unroll
        for (int k = 0; k < 9; ++k) {
            float dx = (float)(mx - nx);
            float dy = (float)(my - ny);
            float sc = fmaf(dx, w0, fmaf(dy, w1, fmaf(dx * dx + dy * dy, w2, bb)));
            e[k] = sc;
            lmax = fmaxf(lmax, sc);
            mx += stepx; my += 2;
            if (mx >= Ww) { mx -= Ww; my += 1; }
        }
#pragma unroll
        for (int off = 32; off; off >>= 1)
            lmax = fmaxf(lmax, __shfl_xor(lmax, off, 64));
        float lsum = 0.f;
#pragma unroll
        for (int k = 0; k < 9; ++k) {
            float ex = __expf(e[k] - lmax);
            e[k] = ex;
            lsum += ex;
        }
#pragma unroll
        for (int off = 32; off; off >>= 1)
            lsum += __shfl_xor(lsum, off, 64);
        const float inv = 1.0f / lsum;

        u16* op = posb + ((size_t)hh * N_ + n) * N_;
#pragma unroll
        for (int k = 0; k < 9; ++k)
            op[k * 64 + lane] = f2bf(e[k] * inv);
    }
}

// ---------------------------------------------------------------------------
// V section of qkvb [m][2304] -> vtb [B,NH,D,N]  (64x64 LDS transpose)
// ---------------------------------------------------------------------------
__global__ __launch_bounds__(256)
void transpose_v_kernel(const u16* __restrict__ qkvb, u16* __restrict__ vtb)
{
    __shared__ u16 t[64 * 72];
    const int n0 = blockIdx.x * 64;
    const int bh = blockIdx.y;
    const int b = bh / NH, h = bh % NH;
    const int tid = threadIdx.x;
    const u16* src = qkvb + ((size_t)b * N_ + n0) * QKV + 2 * C_ + h * D_;
#pragma unroll
    for (int p = 0; p < 2; ++p) {
        int idx = p * 256 + tid;
        int r = idx >> 3, c = (idx & 7) << 3;
        *(uint4*)&t[r * 72 + c] = *(const uint4*)(src + (size_t)r * QKV + c);
    }
    __syncthreads();
    u16* dst = vtb + (size_t)bh * D_ * N_ + n0;
#pragma unroll
    for (int p = 0; p < 2; ++p) {
        int idx = p * 256 + tid;
        int dd = idx >> 3, n8 = (idx & 7) << 3;
        u16 o[8];
#pragma unroll
        for (int j = 0; j < 8; ++j) o[j] = t[(n8 + j) * 72 + dd];
        *(uint4*)(dst + (size_t)dd * N_ + n8) = *(const uint4*)o;
    }
}

// ---------------------------------------------------------------------------
// bf16 MFMA GEMM: 128x128 tile, BK=64, 4 waves, 4x4 16x16x32 per wave.
// XOR-swizzled LDS staging (source-side pre-swizzle, linear LDS dest).
// XCD-chunked block swizzle (nwg % 8 == 0 at both call sites).
// mode 0: out fp32 [M][768] + bias (projection)
// mode 1: outb bf16 [M][2304], Q section (tn<768) scaled by 0.125
// ---------------------------------------------------------------------------
__global__ __launch_bounds__(256)
void mfma_gemm(const u16* __restrict__ A,
               const u16* __restrict__ BT,
               const float* __restrict__ bias,
               float* __restrict__ out,
               u16* __restrict__ outb,
               int ldo, int mode)
{
    const int K = C_;
    __shared__ __align__(16) u16 As[128 * 64];
    __shared__ __align__(16) u16 Bs[128 * 64];
    const int tid = threadIdx.x;
    const int wave = tid >> 6, lane = tid & 63;
    const int quad = lane >> 4, l16 = lane & 15;
    const int wy = wave >> 1, wx = wave & 1;

    // XCD swizzle: nwg % 8 == 0 at both call sites (1296, 432)
    const int gx = gridDim.x;
    const int nwg = gx * gridDim.y;
    int o = blockIdx.y * gx + blockIdx.x;
    o = (o & 7) * (nwg >> 3) + (o >> 3);
    const int tm = (o / gx) * 128, tn = (o % gx) * 128;

    const int lr = lane >> 3;            // row within 8-row staging group
    const int sc = ((lane & 7) ^ lr) * 8; // swizzled source col (elems)

    f32x4 acc[4][4];
#pragma unroll
    for (int i = 0; i < 4; ++i)
#pragma unroll
        for (int j = 0; j < 4; ++j)
            acc[i][j] = (f32x4){0.f, 0.f, 0.f, 0.f};

    for (int k0 = 0; k0 < K; k0 += 64) {
        __syncthreads();
#pragma unroll
        for (int t = 0; t < 4; ++t) {
            const int rg = wave * 32 + t * 8;
            gload16(A  + (size_t)(tm + rg + lr) * K + k0 + sc, &As[rg * 64]);
            gload16(BT + (size_t)(tn + rg + lr) * K + k0 + sc, &Bs[rg * 64]);
        }
        __syncthreads();

#pragma unroll
        for (int kh = 0; kh < 2; ++kh) {
            bf16x8 aA[4], bB[4];
#pragma unroll
            for (int i = 0; i < 4; ++i) {
                const int s = (kh * 4 + quad) ^ (l16 & 7);
                aA[i] = ldsF8a(&As[(wy * 64 + i * 16 + l16) * 64 + s * 8]);
            }
#pragma unroll
            for (int j = 0; j < 4; ++j) {
                const int s = (kh * 4 + quad) ^ (l16 & 7);
                bB[j] = ldsF8a(&Bs[(wx * 64 + j * 16 + l16) * 64 + s * 8]);
            }
#pragma unroll
            for (int i = 0; i < 4; ++i)
#pragma unroll
                for (int j = 0; j < 4; ++j)
                    acc[i][j] = __builtin_amdgcn_mfma_f32_16x16x32_bf16(aA[i], bB[j], acc[i][j], 0, 0, 0);
        }
    }

    if (mode == 0) {
#pragma unroll
        for (int i = 0; i < 4; ++i) {
#pragma unroll
            for (int r = 0; r < 4; ++r) {
                const int m = tm + wy * 64 + i * 16 + quad * 4 + r;
#pragma unroll
                for (int j = 0; j < 4; ++j) {
                    const int c = tn + wx * 64 + j * 16 + l16;
                    out[(size_t)m * ldo + c] = acc[i][j][r] + bias[c];
                }
            }
        }
    } else {
        const float scale = (tn < C_) ? 0.125f : 1.0f;
#pragma unroll
        for (int i = 0; i < 4; ++i) {
#pragma unroll
            for (int r = 0; r < 4; ++r) {
                const int m = tm + wy * 64 + i * 16 + quad * 4 + r;
#pragma unroll
                for (int j = 0; j < 4; ++j) {
                    const int c = tn + wx * 64 + j * 16 + l16;
                    outb[(size_t)m * ldo + c] = f2bf(acc[i][j][r] * scale);
                }
            }
        }
    }
}

// ---------------------------------------------------------------------------
// Flash-style MFMA attention, no online softmax (scores |s|<~4 by construction,
// exp overflow-safe; normalization at end).  Register-double-buffered staging.
// XCD-chunked dispatch swizzle (1728 % 8 == 0) for K/V/pos L2 residency.
// s_setprio(1) wraps the MFMA clusters (T5): ~4+ independent blocks/CU at
// uncorrelated phases -> the CU scheduler favors MFMA-issuing waves over
// other blocks' staging/exp waves.
// ---------------------------------------------------------------------------
__global__ __launch_bounds__(256)
void attn_kernel(const u16* __restrict__ qkvb,
                 const u16* __restrict__ vt,
                 const u16* __restrict__ pos,
                 const float* __restrict__ gating,
                 u16* __restrict__ ao)
{
    const int gx = gridDim.x;                   // 9
    const int nwg = gx * gridDim.y;             // 1728
    int o = blockIdx.y * gx + blockIdx.x;
    o = (o & 7) * (nwg >> 3) + (o >> 3);        // XCD-chunked, bijective
    const int qt = o % gx;
    const int yb = o / gx;                      // h*16 + b  (h-major)
    const int h = yb >> 4, b = yb & 15;
    const int tid = threadIdx.x;
    const int wave = tid >> 6, lane = tid & 63;
    const int quad = lane >> 4, l16 = lane & 15;

    __shared__ u16 smem[4 * 64 * STR];
    u16* Kt = smem;                  // K tile   [m'][d]
    u16* Vs = smem + 64 * STR;       // V^T tile [dd][m']
    u16* Pp = smem + 2 * 64 * STR;   // pos tile [qr][m']
    u16* Pb = smem + 3 * 64 * STR;   // Q tile during prologue, then P tile

    const u16* qptr  = qkvb + ((size_t)b * N_ + qt * 64) * QKV + h * D_;
    const u16* kbase = qkvb + (size_t)b * N_ * QKV + C_ + h * D_;
    const u16* vbase = vt + (size_t)(b * NH + h) * D_ * N_;   // vtb layout key
    const u16* pbase = pos + ((size_t)h * N_ + qt * 64) * N_;

    const int sr = tid >> 3;            // 0..31 (two passes cover 64 rows)
    const int scol = (tid & 7) << 3;    // 0..56

    // stage Q into Pb (direct)
#pragma unroll
    for (int p = 0; p < 2; ++p) {
        int r = p * 32 + sr;
        uint4 d = *(const uint4*)(qptr + (size_t)r * QKV + scol);
        *(uint2*)&Pb[r * STR + scol]     = make_uint2(d.x, d.y);
        *(uint2*)&Pb[r * STR + scol + 4] = make_uint2(d.z, d.w);
    }
    __syncthreads();

    const int arow = wave * 16 + l16;
    bf16x8 aq0 = ldsF8u(&Pb[arow * STR + quad * 8]);
    bf16x8 aq1 = ldsF8u(&Pb[arow * STR + 32 + quad * 8]);

    uint4 rk[2], rv[2], rp[2];
    auto loadT = [&](int m0) {
#pragma unroll
        for (int p = 0; p < 2; ++p) {
            int r = p * 32 + sr;
            rk[p] = *(const uint4*)(kbase + (size_t)(m0 + r) * QKV + scol);
            rv[p] = *(const uint4*)(vbase + (size_t)r * N_ + m0 + scol);
            rp[p] = *(const uint4*)(pbase + (size_t)r * N_ + m0 + scol);
        }
    };
    auto writeT = [&]() {
#pragma unroll
        for (int p = 0; p < 2; ++p) {
            int r = p * 32 + sr;
            *(uint2*)&Kt[r * STR + scol]     = make_uint2(rk[p].x, rk[p].y);
            *(uint2*)&Kt[r * STR + scol + 4] = make_uint2(rk[p].z, rk[p].w);
            *(uint2*)&Vs[r * STR + scol]     = make_uint2(rv[p].x, rv[p].y);
            *(uint2*)&Vs[r * STR + scol + 4] = make_uint2(rv[p].z, rv[p].w);
            *(uint2*)&Pp[r * STR + scol]     = make_uint2(rp[p].x, rp[p].y);
            *(uint2*)&Pp[r * STR + scol + 4] = make_uint2(rp[p].z, rp[p].w);
        }
    };

    loadT(0);

    f32x4 oc[4], op[4];
#pragma unroll
    for (int nt = 0; nt < 4; ++nt) {
        oc[nt] = (f32x4){0.f, 0.f, 0.f, 0.f};
        op[nt] = (f32x4){0.f, 0.f, 0.f, 0.f};
    }
    float lrun[4] = {0.f, 0.f, 0.f, 0.f};

    for (int mt = 0; mt < 9; ++mt) {
        // prev compute's LDS reads done (and, at mt=0, Q frag reads done)
        __syncthreads();
        writeT();
        __syncthreads();
        if (mt < 8) loadT((mt + 1) * 64);   // async; consumed next iter

        // S = Q @ K^T
        f32x4 s[4];
        __builtin_amdgcn_s_setprio(1);
#pragma unroll
        for (int nt = 0; nt < 4; ++nt) {
            bf16x8 b0 = ldsF8u(&Kt[(nt * 16 + l16) * STR + quad * 8]);
            bf16x8 b1 = ldsF8u(&Kt[(nt * 16 + l16) * STR + 32 + quad * 8]);
            f32x4 z = (f32x4){0.f, 0.f, 0.f, 0.f};
            z = __builtin_amdgcn_mfma_f32_16x16x32_bf16(aq0, b0, z, 0, 0, 0);
            z = __builtin_amdgcn_mfma_f32_16x16x32_bf16(aq1, b1, z, 0, 0, 0);
            s[nt] = z;
        }
        __builtin_amdgcn_s_setprio(0);

        // P = exp(S); per-lane partial row sums
#pragma unroll
        for (int r = 0; r < 4; ++r) {
            const int prow = (wave * 16 + quad * 4 + r) * STR;
            float e0 = __expf(s[0][r]);
            float e1 = __expf(s[1][r]);
            float e2 = __expf(s[2][r]);
            float e3 = __expf(s[3][r]);
            Pb[prow +  0 + l16] = f2bf(e0);
            Pb[prow + 16 + l16] = f2bf(e1);
            Pb[prow + 32 + l16] = f2bf(e2);
            Pb[prow + 48 + l16] = f2bf(e3);
            lrun[r] += (e0 + e1) + (e2 + e3);
        }
        asm volatile("s_waitcnt lgkmcnt(0)" ::: "memory");  // wave-local P drain

        // O_c += P @ V ; O_p += pos @ V
        __builtin_amdgcn_s_setprio(1);
#pragma unroll
        for (int ks = 0; ks < 2; ++ks) {
            bf16x8 ap   = ldsF8u(&Pb[arow * STR + ks * 32 + quad * 8]);
            bf16x8 apos = ldsF8u(&Pp[arow * STR + ks * 32 + quad * 8]);
#pragma unroll
            for (int nt = 0; nt < 4; ++nt) {
                bf16x8 bv = ldsF8u(&Vs[(nt * 16 + l16) * STR + ks * 32 + quad * 8]);
                oc[nt] = __builtin_amdgcn_mfma_f32_16x16x32_bf16(ap,   bv, oc[nt], 0, 0, 0);
                op[nt] = __builtin_amdgcn_mfma_f32_16x16x32_bf16(apos, bv, op[nt], 0, 0, 0);
            }
        }
        __builtin_amdgcn_s_setprio(0);
    }

#pragma unroll
    for (int r = 0; r < 4; ++r) {
        lrun[r] += __shfl_xor(lrun[r], 1, 64);
        lrun[r] += __shfl_xor(lrun[r], 2, 64);
        lrun[r] += __shfl_xor(lrun[r], 4, 64);
        lrun[r] += __shfl_xor(lrun[r], 8, 64);
    }

    const float g = 1.f / (1.f + __expf(-gating[h]));
#pragma unroll
    for (int r = 0; r < 4; ++r) {
        const float sc = (1.f - g) / lrun[r];
        const int row = qt * 64 + wave * 16 + quad * 4 + r;
#pragma unroll
        for (int nt = 0; nt < 4; ++nt) {
            ao[((size_t)b * N_ + row) * C_ + h * D_ + nt * 16 + l16] =
                f2bf(oc[nt][r] * sc + g * op[nt][r]);
        }
    }
}

// ---------------------------------------------------------------------------
extern "C" void kernel_launch(void* const* d_in, const int* in_sizes, int n_in,
                              void* d_out, int out_size, void* d_ws, size_t ws_size,
                              hipStream_t stream)
{
    const float* x      = (const float*)d_in[0];
    const float* Wq     = (const float*)d_in[1];
    const float* Wk     = (const float*)d_in[2];
    const float* Wv     = (const float*)d_in[3];
    const float* Wproj  = (const float*)d_in[4];
    const float* bproj  = (const float*)d_in[5];
    const float* pos_w  = (const float*)d_in[6];
    const float* pos_b  = (const float*)d_in[7];
    const float* gating = (const float*)d_in[8];
    const int*   Wp     = (const int*)d_in[10];
    float* out = (float*)d_out;

    const size_t xe = (size_t)B_ * N_ * C_;        // 7,077,888
    const size_t we = (size_t)C_ * C_;             // 589,824
    const size_t qe = (size_t)B_ * N_ * QKV;       // 21,233,664
    const size_t pe = (size_t)NH * N_ * N_;        // 3,981,312
    u16* xb   = (u16*)d_ws;
    u16* wt   = xb + xe;            // packed [2304][768]: WqT | WkT | WvT
    u16* wtp  = wt + 3 * we;        // WprojT
    u16* qkvb = wtp + we;           // [M][2304] bf16: Q | K | V
    u16* vtb  = qkvb + qe;          // [B,NH,D,N]
    u16* posb = vtb + xe;
    u16* aob  = posb + pe;
    size_t need = (size_t)(3 * xe + 4 * we + qe + pe) * sizeof(u16);  // ~97.6 MB
    if (ws_size < need) return;

    // fused prep: conv_x | 4x transpose_w | pos_softmax  (1 launch, 5760 blocks)
    prep_kernel<<<dim3(5760), 256, 0, stream>>>(x, Wq, Wk, Wv, Wproj,
                                                pos_w, pos_b, Wp,
                                                xb, wt, wtp, posb);
    // fused QKV: bf16 [9216][2304]
    mfma_gemm<<<dim3(18, 72), 256, 0, stream>>>(xb, wt, nullptr, nullptr,
                                                qkvb, QKV, 1);
    transpose_v_kernel<<<dim3(9, B_ * NH), 256, 0, stream>>>(qkvb, vtb);
    attn_kernel<<<dim3(9, NH * B_), 256, 0, stream>>>(qkvb, vtb, posb, gating, aob);
    // projection: fp32 out + bias
    mfma_gemm<<<dim3(6, 72), 256, 0, stream>>>(aob, wtp, bproj, out,
                                               nullptr, C_, 0);
}